// Round 10
// baseline (427.197 us; speedup 1.0000x reference)
//
#include <hip/hip_runtime.h>

#define NODES 50000
#define NEDGES 800000
#define NIN 512
#define NHID 64

#define NB 391        // coarse buckets: row >> 7, 128 rows each (391*128 >= 50000)
#define BCAP 2560     // per-bucket edge capacity (mean 2046, +11 sigma)
#define EB 4096       // edges per binA block
#define NBA 196       // binA blocks: 196*4096 >= 800000
#define GEMM_BLKS 3125

typedef __attribute__((ext_vector_type(8))) short short8v;           // 8 bf16
typedef __attribute__((ext_vector_type(4))) float f32x4;

// ws layout in 4-byte words
#define H_OFF    0          // 1,600,000 words: h bf16 (3.2M elems)
#define WBF_OFF  1600000    // 16,384 words: W bf16
#define GCUR_OFF 1616384    // 512 words: bucket cursors (391 used)
#define ECV2_OFF 1616896    // 2,001,920 words: NB x BCAP x int2(packed rl|col, val)
// end = 3,618,816 words = 14.5 MB

__device__ inline unsigned short f2bf(float f) {
  unsigned u = __builtin_bit_cast(unsigned, f);
  u += 0x7FFF + ((u >> 16) & 1);          // RNE
  return (unsigned short)(u >> 16);
}
__device__ inline float bf2f(unsigned short u) {
  return __builtin_bit_cast(float, (unsigned)u << 16);
}

// ---------- fused init: zero gcur + W fp32->bf16 ----------
__global__ __launch_bounds__(256) void init_kernel(
    const float* __restrict__ W, unsigned int* __restrict__ wbf,
    int* __restrict__ gcur)
{
  int i = blockIdx.x * 256 + threadIdx.x;
  if (i < NIN * NHID / 2) {
    float2 w = reinterpret_cast<const float2*>(W)[i];
    wbf[i] = (unsigned)f2bf(w.x) | ((unsigned)f2bf(w.y) << 16);
  }
  if (i < NB) gcur[i] = 0;
}

// ---------- fat: blocks [0,NBA) = coarse binning; [NBA, NBA+3125) = gemm -----
__global__ __launch_bounds__(64) void fat_kernel(
    const float* __restrict__ x, const unsigned short* __restrict__ wbf,
    const float* __restrict__ b, unsigned short* __restrict__ h,
    const int* __restrict__ rows, const int* __restrict__ cols,
    const float* __restrict__ vals, int* __restrict__ gcur,
    int2* __restrict__ ecv2)
{
  __shared__ int hist[NB];                 // per-block bucket counts -> bases
  __shared__ unsigned short slots[EB];     // per-edge local slot
  int bid = blockIdx.x;
  int tid = (int)threadIdx.x;

  if (bid < NBA) {
    // ---------------- binA: LDS histogram + one reservation atomic/bucket ---
    int e0 = bid * EB;
    for (int i = tid; i < NB; i += 64) hist[i] = 0;
    __syncthreads();
    // sweep 1: count, record local slot (LDS atomic return = order in block)
    #pragma unroll 4
    for (int k = 0; k < EB / 64; ++k) {
      int i = e0 + k * 64 + tid;
      if (i < NEDGES) {
        int r = rows[i];
        int s = atomicAdd(&hist[r >> 7], 1);
        slots[k * 64 + tid] = (unsigned short)s;
      }
    }
    __syncthreads();
    // reserve contiguous ranges in each bucket (one global atomic per bucket)
    for (int i = tid; i < NB; i += 64) {
      int c = hist[i];
      hist[i] = c ? atomicAdd(&gcur[i], c) : 0;
    }
    __syncthreads();
    // sweep 2: scatter (runs of ~10 edges per bucket -> coalescing in L2)
    #pragma unroll 4
    for (int k = 0; k < EB / 64; ++k) {
      int i = e0 + k * 64 + tid;
      if (i < NEDGES) {
        int r = rows[i];
        int bkt = r >> 7;
        int sl = hist[bkt] + (int)slots[k * 64 + tid];
        if (sl < BCAP)
          ecv2[(long)bkt * BCAP + sl] =
              make_int2(cols[i] | ((r & 127) << 17), __float_as_int(vals[i]));
      }
    }
    return;
  }

  // ---------------- gemm: one wave per 16 nodes, K strip preloaded ----------
  int gw = bid - NBA;
  int lane = tid & 63;
  int r16 = lane & 15;                // A-row / D-col select
  int kg  = lane >> 4;                // k-group 0..3

  const float4* xp = reinterpret_cast<const float4*>(
      x + (long)(gw * 16 + r16) * NIN + kg * 8);
  const unsigned short* wp = wbf + (long)r16 * NIN + kg * 8;

  float4 xb[32];
  #pragma unroll
  for (int s = 0; s < 16; ++s) {
    xb[2 * s]     = xp[8 * s];
    xb[2 * s + 1] = xp[8 * s + 1];
  }
  // pin: all 32 loads issued before any consume (forces ~128 VGPRs of MLP)
  __builtin_amdgcn_sched_barrier(0);

  f32x4 acc[4] = {{0,0,0,0},{0,0,0,0},{0,0,0,0},{0,0,0,0}};

  #pragma unroll
  for (int s = 0; s < 16; ++s) {
    float4 a0 = xb[2 * s];
    float4 a1 = xb[2 * s + 1];
    short8v af;
    af[0] = (short)f2bf(a0.x); af[1] = (short)f2bf(a0.y);
    af[2] = (short)f2bf(a0.z); af[3] = (short)f2bf(a0.w);
    af[4] = (short)f2bf(a1.x); af[5] = (short)f2bf(a1.y);
    af[6] = (short)f2bf(a1.z); af[7] = (short)f2bf(a1.w);
    #pragma unroll
    for (int ft = 0; ft < 4; ++ft) {
      short8v bfr = *reinterpret_cast<const short8v*>(
          wp + (long)ft * 16 * NIN + s * 32);
      acc[ft] = __builtin_amdgcn_mfma_f32_16x16x32_bf16(af, bfr, acc[ft], 0, 0, 0);
    }
  }

  // D: col(f) = lane&15, row(node) = kg*4 + reg
  int n0 = gw * 16 + kg * 4;
  #pragma unroll
  for (int ft = 0; ft < 4; ++ft) {
    float bias = b[ft * 16 + r16];
    #pragma unroll
    for (int r = 0; r < 4; ++r)
      h[(long)(n0 + r) * NHID + ft * 16 + r16] = f2bf(acc[ft][r] + bias);
  }
}

// ---------- passB: block per bucket, LDS fp32 accumulate, +LeakyReLU --------
// 256 thr = 16 edge-groups x 16 lanes; lane covers 4 features (ushort4 of h).
// acc swizzle: word f' = f ^ ((rl&7)<<2) -> concurrent edge-groups spread
// across 8 bank classes (2-way max, free per m136).
__global__ __launch_bounds__(256) void passB_kernel(
    const int* __restrict__ gcur, const int2* __restrict__ ecv2,
    const unsigned short* __restrict__ h, const float* __restrict__ alpha,
    float* __restrict__ out)
{
  __shared__ float acc[128 * 64];   // 32 KB
  int bkt = blockIdx.x;
  int tid = (int)threadIdx.x;

  #pragma unroll
  for (int i = 0; i < 32; ++i) acc[i * 256 + tid] = 0.0f;
  __syncthreads();

  int n = gcur[bkt];
  if (n > BCAP) n = BCAP;
  const int2* base = ecv2 + (long)bkt * BCAP;

  int g = tid >> 4;          // edge group 0..15
  int l = tid & 15;          // lane in group: features l*4 .. l*4+3

  #pragma unroll 2
  for (int i = g; i < n; i += 16) {
    int2 e = base[i];
    int col = e.x & 0x1FFFF;
    int rl  = e.x >> 17;
    float v = __int_as_float(e.y);
    ushort4 hv = *reinterpret_cast<const ushort4*>(&h[col * NHID + l * 4]);
    int wb = rl * 64 + ((l * 4) ^ ((rl & 7) << 2));
    atomicAdd(&acc[wb + 0], v * bf2f(hv.x));
    atomicAdd(&acc[wb + 1], v * bf2f(hv.y));
    atomicAdd(&acc[wb + 2], v * bf2f(hv.z));
    atomicAdd(&acc[wb + 3], v * bf2f(hv.w));
  }
  __syncthreads();

  // epilogue: unswizzle, LeakyReLU, coalesced store
  float a = alpha[0];
  int rl2 = tid >> 1;
  int hh  = tid & 1;
  int row = bkt * 128 + rl2;
  if (row < NODES) {
    const float4* acc4 = reinterpret_cast<const float4*>(acc);
    float4* out4 = reinterpret_cast<float4*>(out);
    #pragma unroll
    for (int j = 0; j < 8; ++j) {
      int c = hh * 8 + j;                       // chunk of 4 features
      float4 v = acc4[rl2 * 16 + (c ^ (rl2 & 7))];
      v.x = v.x >= 0.f ? v.x : a * v.x;
      v.y = v.y >= 0.f ? v.y : a * v.y;
      v.z = v.z >= 0.f ? v.z : a * v.z;
      v.w = v.w >= 0.f ? v.w : a * v.w;
      out4[(long)row * 16 + c] = v;
    }
  }
}

extern "C" void kernel_launch(void* const* d_in, const int* in_sizes, int n_in,
                              void* d_out, int out_size, void* d_ws, size_t ws_size,
                              hipStream_t stream) {
  const float* x     = (const float*)d_in[0];
  const int*   rows  = (const int*)d_in[1];
  const int*   cols  = (const int*)d_in[2];
  const float* vals  = (const float*)d_in[3];
  const float* W     = (const float*)d_in[4];
  const float* b     = (const float*)d_in[5];
  const float* alpha = (const float*)d_in[6];
  float* out = (float*)d_out;

  float* wsf = (float*)d_ws;
  unsigned short* h    = (unsigned short*)(wsf + H_OFF);
  unsigned int*   wbf  = (unsigned int*)(wsf + WBF_OFF);
  int*            gcur = (int*)(wsf + GCUR_OFF);
  int2*           ecv2 = (int2*)(wsf + ECV2_OFF);

  init_kernel<<<64, 256, 0, stream>>>(W, wbf, gcur);
  fat_kernel<<<NBA + GEMM_BLKS, 64, 0, stream>>>(
      x, (const unsigned short*)wbf, b, h, rows, cols, vals, gcur, ecv2);
  passB_kernel<<<NB, 256, 0, stream>>>(gcur, ecv2, h, alpha, out);
}

// Round 11
// 119.948 us; speedup vs baseline: 3.5615x; 3.5615x over previous
//
#include <hip/hip_runtime.h>

#define NODES 50000
#define NEDGES 800000
#define NIN 512
#define NHID 64

#define NB 391        // coarse buckets: row >> 7, 128 rows each
#define BCAP 2560     // per-bucket edge capacity (mean 2046, +11 sigma)
#define EB 4096       // edges per binA block
#define NBA 196       // binA blocks: 196*4096 >= 800000
#define GEMM_BLKS 3125

typedef __attribute__((ext_vector_type(8))) short short8v;           // 8 bf16
typedef __attribute__((ext_vector_type(8))) unsigned short ushort8v; // 8 bf16
typedef __attribute__((ext_vector_type(4))) float f32x4;
typedef __attribute__((ext_vector_type(4))) unsigned int uint4v;

// ws layout in 4-byte words
#define H_OFF    0          // 1,600,000 words: h bf16 (3.2M elems)
#define WBF_OFF  1600000    // 16,384 words: W bf16
#define GCUR_OFF 1616384    // 512 words: bucket cursors
#define RMETA_OFF 1616896   // 100,000 words: int2 {start, deg} per row
#define ECV2_OFF 1716896    // 2,001,920 words: NB x BCAP x int2
// end = 3,718,816 words = 14.9 MB

__device__ inline unsigned short f2bf(float f) {
  unsigned u = __builtin_bit_cast(unsigned, f);
  u += 0x7FFF + ((u >> 16) & 1);          // RNE
  return (unsigned short)(u >> 16);
}
__device__ inline float bf2f(unsigned short u) {
  return __builtin_bit_cast(float, (unsigned)u << 16);
}

// ---------- fused init: zero gcur + W fp32->bf16 ----------
__global__ __launch_bounds__(256) void init_kernel(
    const float* __restrict__ W, unsigned int* __restrict__ wbf,
    int* __restrict__ gcur)
{
  int i = blockIdx.x * 256 + threadIdx.x;
  if (i < NIN * NHID / 2) {
    float2 w = reinterpret_cast<const float2*>(W)[i];
    wbf[i] = (unsigned)f2bf(w.x) | ((unsigned)f2bf(w.y) << 16);
  }
  if (i < NB) gcur[i] = 0;
}

// ---------- fat: blocks [0,NBA) = coarse binning; rest = MFMA gemm ----------
__global__ __launch_bounds__(64) void fat_kernel(
    const float* __restrict__ x, const unsigned short* __restrict__ wbf,
    const float* __restrict__ b, unsigned short* __restrict__ h,
    const int* __restrict__ rows, const int* __restrict__ cols,
    const float* __restrict__ vals, int* __restrict__ gcur,
    int2* __restrict__ ecv2)
{
  __shared__ int hist[NB];                 // per-block bucket counts -> bases
  __shared__ unsigned short slots[EB];     // per-edge local slot
  int bid = blockIdx.x;
  int tid = (int)threadIdx.x;

  if (bid < NBA) {
    // binA: LDS histogram (int atomics, native) + 1 reservation atomic/bucket
    int e0 = bid * EB;
    for (int i = tid; i < NB; i += 64) hist[i] = 0;
    __syncthreads();
    #pragma unroll 4
    for (int k = 0; k < EB / 64; ++k) {
      int i = e0 + k * 64 + tid;
      if (i < NEDGES) {
        int r = rows[i];
        int s = atomicAdd(&hist[r >> 7], 1);
        slots[k * 64 + tid] = (unsigned short)s;
      }
    }
    __syncthreads();
    for (int i = tid; i < NB; i += 64) {
      int c = hist[i];
      hist[i] = c ? atomicAdd(&gcur[i], c) : 0;
    }
    __syncthreads();
    // scatter: ~10-edge runs per bucket -> mostly coalesced lines
    #pragma unroll 4
    for (int k = 0; k < EB / 64; ++k) {
      int i = e0 + k * 64 + tid;
      if (i < NEDGES) {
        int r = rows[i];
        int bkt = r >> 7;
        int sl = hist[bkt] + (int)slots[k * 64 + tid];
        if (sl < BCAP)
          ecv2[(long)bkt * BCAP + sl] =
              make_int2(cols[i] | ((r & 127) << 17), __float_as_int(vals[i]));
      }
    }
    return;
  }

  // gemm: one wave per 16 nodes; K=512 strip preloaded, pinned before MFMA
  int gw = bid - NBA;
  int lane = tid & 63;
  int r16 = lane & 15;                // A-row / D-col select
  int kg  = lane >> 4;                // k-group 0..3

  const float4* xp = reinterpret_cast<const float4*>(
      x + (long)(gw * 16 + r16) * NIN + kg * 8);
  const unsigned short* wp = wbf + (long)r16 * NIN + kg * 8;

  float4 xb[32];
  #pragma unroll
  for (int s = 0; s < 16; ++s) {
    xb[2 * s]     = xp[8 * s];
    xb[2 * s + 1] = xp[8 * s + 1];
  }
  __builtin_amdgcn_sched_barrier(0);   // keep all 32 loads issued up front

  f32x4 acc[4] = {{0,0,0,0},{0,0,0,0},{0,0,0,0},{0,0,0,0}};

  #pragma unroll
  for (int s = 0; s < 16; ++s) {
    float4 a0 = xb[2 * s];
    float4 a1 = xb[2 * s + 1];
    unsigned p0, p1, p2, p3;   // v_cvt_pk_bf16_f32: lo=src0, hi=src1 (RNE)
    asm("v_cvt_pk_bf16_f32 %0, %1, %2" : "=v"(p0) : "v"(a0.x), "v"(a0.y));
    asm("v_cvt_pk_bf16_f32 %0, %1, %2" : "=v"(p1) : "v"(a0.z), "v"(a0.w));
    asm("v_cvt_pk_bf16_f32 %0, %1, %2" : "=v"(p2) : "v"(a1.x), "v"(a1.y));
    asm("v_cvt_pk_bf16_f32 %0, %1, %2" : "=v"(p3) : "v"(a1.z), "v"(a1.w));
    uint4v ap = {p0, p1, p2, p3};
    short8v af = __builtin_bit_cast(short8v, ap);
    #pragma unroll
    for (int ft = 0; ft < 4; ++ft) {
      short8v bfr = *reinterpret_cast<const short8v*>(
          wp + (long)ft * 16 * NIN + s * 32);
      acc[ft] = __builtin_amdgcn_mfma_f32_16x16x32_bf16(af, bfr, acc[ft], 0, 0, 0);
    }
  }

  // D: col(f) = lane&15, row(node) = kg*4 + reg
  int n0 = gw * 16 + kg * 4;
  #pragma unroll
  for (int ft = 0; ft < 4; ++ft) {
    float bias = b[ft * 16 + r16];
    #pragma unroll
    for (int r = 0; r < 4; ++r)
      h[(long)(n0 + r) * NHID + ft * 16 + r16] = f2bf(acc[ft][r] + bias);
  }
}

// ---------- sortb: counting-sort each bucket by row-local index -------------
// Only INT LDS atomics (native). Writes back row-sorted edges (pure col in
// e.x) + rowmeta {start, deg}. All traffic in a 20KB L2-resident window.
__global__ __launch_bounds__(256) void sortb_kernel(
    const int* __restrict__ gcur, int2* __restrict__ ecv2,
    int2* __restrict__ rowmeta)
{
  __shared__ int2 ed[BCAP];               // 20.5 KB
  __shared__ unsigned short slots[BCAP];  // 5 KB
  __shared__ int hist[128], base[128], stmp[128];
  int bkt = blockIdx.x;
  int tid = (int)threadIdx.x;

  int n = gcur[bkt];
  if (n > BCAP) n = BCAP;
  int2* bptr = ecv2 + (long)bkt * BCAP;

  if (tid < 128) hist[tid] = 0;
  __syncthreads();

  for (int i = tid; i < n; i += 256) {
    int2 e = bptr[i];
    ed[i] = e;
    int rl = e.x >> 17;
    slots[i] = (unsigned short)atomicAdd(&hist[rl], 1);
  }
  __syncthreads();

  // exclusive scan of hist[0..127]
  int v = (tid < 128) ? hist[tid] : 0;
  if (tid < 128) stmp[tid] = v;
  __syncthreads();
  for (int d = 1; d < 128; d <<= 1) {
    int t = (tid < 128 && tid >= d) ? stmp[tid - d] : 0;
    __syncthreads();
    if (tid < 128) stmp[tid] += t;
    __syncthreads();
  }
  if (tid < 128) base[tid] = stmp[tid] - v;
  __syncthreads();

  // scatter back sorted (8B stores within 20KB window -> L2-resident)
  for (int i = tid; i < n; i += 256) {
    int2 e = ed[i];
    int rl = e.x >> 17;
    int pos = base[rl] + (int)slots[i];
    bptr[pos] = make_int2(e.x & 0x1FFFF, e.y);
  }

  if (tid < 128) {
    int row = bkt * 128 + tid;
    if (row < NODES)
      rowmeta[row] = make_int2(bkt * BCAP + base[tid], hist[tid]);
  }
}

// ---------- gather: wave per row, 8 edges in flight, +LeakyReLU -------------
__global__ __launch_bounds__(256) void gather_kernel(
    const int2* __restrict__ rowmeta, const int2* __restrict__ ecv2,
    const unsigned short* __restrict__ h, const float* __restrict__ alpha,
    float* __restrict__ out)
{
  int wid = (int)((blockIdx.x * 256 + threadIdx.x) >> 6);
  if (wid >= NODES) return;
  int lane = (int)(threadIdx.x & 63);
  int eg = lane >> 3;          // edge group 0..7
  int fo = lane & 7;           // feature octet 0..7
  int2 m = rowmeta[wid];
  int deg = m.y;
  const int2* base = ecv2 + m.x;
  float a = alpha[0];

  float acc[8] = {0.f, 0.f, 0.f, 0.f, 0.f, 0.f, 0.f, 0.f};
  int j = eg;
  int2 e = (j < deg) ? base[j] : make_int2(0, 0);
  while (j < deg) {
    int2 en = (j + 8 < deg) ? base[j + 8] : make_int2(0, 0);   // prefetch
    float v = __int_as_float(e.y);
    ushort8v hv = *reinterpret_cast<const ushort8v*>(&h[(long)e.x * NHID + fo * 8]);
    #pragma unroll
    for (int k = 0; k < 8; ++k)
      acc[k] = fmaf(v, bf2f(hv[k]), acc[k]);
    e = en;
    j += 8;
  }

  #pragma unroll
  for (int k = 0; k < 8; ++k) {
    acc[k] += __shfl_xor(acc[k], 8);
    acc[k] += __shfl_xor(acc[k], 16);
    acc[k] += __shfl_xor(acc[k], 32);
  }

  if (eg == 0) {
    float4 o0, o1;
    o0.x = acc[0] >= 0.f ? acc[0] : a * acc[0];
    o0.y = acc[1] >= 0.f ? acc[1] : a * acc[1];
    o0.z = acc[2] >= 0.f ? acc[2] : a * acc[2];
    o0.w = acc[3] >= 0.f ? acc[3] : a * acc[3];
    o1.x = acc[4] >= 0.f ? acc[4] : a * acc[4];
    o1.y = acc[5] >= 0.f ? acc[5] : a * acc[5];
    o1.z = acc[6] >= 0.f ? acc[6] : a * acc[6];
    o1.w = acc[7] >= 0.f ? acc[7] : a * acc[7];
    *reinterpret_cast<float4*>(&out[(long)wid * NHID + fo * 8]) = o0;
    *reinterpret_cast<float4*>(&out[(long)wid * NHID + fo * 8 + 4]) = o1;
  }
}

extern "C" void kernel_launch(void* const* d_in, const int* in_sizes, int n_in,
                              void* d_out, int out_size, void* d_ws, size_t ws_size,
                              hipStream_t stream) {
  const float* x     = (const float*)d_in[0];
  const int*   rows  = (const int*)d_in[1];
  const int*   cols  = (const int*)d_in[2];
  const float* vals  = (const float*)d_in[3];
  const float* W     = (const float*)d_in[4];
  const float* b     = (const float*)d_in[5];
  const float* alpha = (const float*)d_in[6];
  float* out = (float*)d_out;

  float* wsf = (float*)d_ws;
  unsigned short* h     = (unsigned short*)(wsf + H_OFF);
  unsigned int*   wbf   = (unsigned int*)(wsf + WBF_OFF);
  int*            gcur  = (int*)(wsf + GCUR_OFF);
  int2*           rmeta = (int2*)(wsf + RMETA_OFF);
  int2*           ecv2  = (int2*)(wsf + ECV2_OFF);

  init_kernel<<<64, 256, 0, stream>>>(W, wbf, gcur);
  fat_kernel<<<NBA + GEMM_BLKS, 64, 0, stream>>>(
      x, (const unsigned short*)wbf, b, h, rows, cols, vals, gcur, ecv2);
  sortb_kernel<<<NB, 256, 0, stream>>>(gcur, ecv2, rmeta);
  gather_kernel<<<NODES * 64 / 256, 256, 0, stream>>>(rmeta, ecv2, h, alpha, out);
}

// Round 12
// 106.124 us; speedup vs baseline: 4.0254x; 1.1303x over previous
//
#include <hip/hip_runtime.h>

#define NODES 50000
#define NEDGES 800000
#define NIN 512
#define NHID 64

#define NB 391        // coarse buckets: row >> 7, 128 rows each
#define BCAP 2560     // per-bucket edge capacity (mean 2046, +11 sigma)
#define EB 4096       // edges per binA block
#define NBA 196       // binA blocks: 196*4096 >= 800000

typedef __attribute__((ext_vector_type(8))) short short8v;           // 8 bf16
typedef __attribute__((ext_vector_type(8))) unsigned short ushort8v; // 8 bf16
typedef __attribute__((ext_vector_type(4))) float f32x4;
typedef __attribute__((ext_vector_type(4))) unsigned int uint4v;

// ws layout in 4-byte words
#define H_OFF    0          // 1,600,000 words: h bf16 (3.2M elems)
#define WBF_OFF  1600000    // 16,384 words: W bf16
#define GCUR_OFF 1616384    // 512 words: bucket cursors
#define RMETA_OFF 1616896   // 100,000 words: int2 {start, deg} per row
#define ECV2_OFF 1716896    // 2,001,920 words: NB x BCAP x int2
// end = 3,718,816 words = 14.9 MB

__device__ inline unsigned short f2bf(float f) {
  unsigned u = __builtin_bit_cast(unsigned, f);
  u += 0x7FFF + ((u >> 16) & 1);          // RNE
  return (unsigned short)(u >> 16);
}
__device__ inline float bf2f(unsigned short u) {
  return __builtin_bit_cast(float, (unsigned)u << 16);
}

// ---------- fused init: zero gcur + W fp32->bf16 ----------
__global__ __launch_bounds__(256) void init_kernel(
    const float* __restrict__ W, unsigned int* __restrict__ wbf,
    int* __restrict__ gcur)
{
  int i = blockIdx.x * 256 + threadIdx.x;
  if (i < NIN * NHID / 2) {
    float2 w = reinterpret_cast<const float2*>(W)[i];
    wbf[i] = (unsigned)f2bf(w.x) | ((unsigned)f2bf(w.y) << 16);
  }
  if (i < NB) gcur[i] = 0;
}

// ---------- binA: coarse binning, LDS histogram, 1 reservation atomic/bucket
__global__ __launch_bounds__(256) void binA_kernel(
    const int* __restrict__ rows, const int* __restrict__ cols,
    const float* __restrict__ vals, int* __restrict__ gcur,
    int2* __restrict__ ecv2)
{
  __shared__ int hist[NB];
  __shared__ unsigned short slots[EB];
  int bid = blockIdx.x;
  int tid = (int)threadIdx.x;
  int e0 = bid * EB;

  for (int i = tid; i < NB; i += 256) hist[i] = 0;
  __syncthreads();
  #pragma unroll 4
  for (int k = 0; k < EB / 256; ++k) {
    int i = e0 + k * 256 + tid;
    if (i < NEDGES) {
      int r = rows[i];
      int s = atomicAdd(&hist[r >> 7], 1);
      slots[k * 256 + tid] = (unsigned short)s;
    }
  }
  __syncthreads();
  for (int i = tid; i < NB; i += 256) {
    int c = hist[i];
    hist[i] = c ? atomicAdd(&gcur[i], c) : 0;
  }
  __syncthreads();
  // scatter: ~10-edge runs per (block,bucket) -> mostly coalesced lines
  #pragma unroll 4
  for (int k = 0; k < EB / 256; ++k) {
    int i = e0 + k * 256 + tid;
    if (i < NEDGES) {
      int r = rows[i];
      int bkt = r >> 7;
      int sl = hist[bkt] + (int)slots[k * 256 + tid];
      if (sl < BCAP)
        ecv2[(long)bkt * BCAP + sl] =
            make_int2(cols[i] | ((r & 127) << 17), __float_as_int(vals[i]));
    }
  }
}

// ---------- MFMA GEMM: standalone, no LDS, forced K-strip preload ----------
// 4 waves/block, one wave per 16 nodes. 32 float4 loads pinned live via
// empty-asm "+v" keep-alives (RA cannot sink/remat past them).
__global__ __launch_bounds__(256, 2) void gemm_kernel(
    const float* __restrict__ x, const unsigned short* __restrict__ wbf,
    const float* __restrict__ b, unsigned short* __restrict__ h)
{
  int gw = blockIdx.x * 4 + ((int)threadIdx.x >> 6);
  if (gw >= NODES / 16) return;       // 3125 waves
  int lane = (int)(threadIdx.x & 63);
  int r16 = lane & 15;                // A-row / D-col select
  int kg  = lane >> 4;                // k-group 0..3

  const float4* xp = reinterpret_cast<const float4*>(
      x + (long)(gw * 16 + r16) * NIN + kg * 8);
  const unsigned short* wp = wbf + (long)r16 * NIN + kg * 8;

  float4 xb[32];
  #pragma unroll
  for (int s = 0; s < 16; ++s) {
    xb[2 * s]     = xp[8 * s];
    xb[2 * s + 1] = xp[8 * s + 1];
  }
  // pin all 128 floats live -> 32 loads actually in flight
  {
    float* xf = reinterpret_cast<float*>(xb);
    #pragma unroll
    for (int i = 0; i < 128; ++i) asm volatile("" : "+v"(xf[i]));
  }
  __builtin_amdgcn_sched_barrier(0);

  f32x4 acc[4] = {{0,0,0,0},{0,0,0,0},{0,0,0,0},{0,0,0,0}};

  #pragma unroll
  for (int s = 0; s < 16; ++s) {
    float4 a0 = xb[2 * s];
    float4 a1 = xb[2 * s + 1];
    unsigned p0, p1, p2, p3;   // v_cvt_pk_bf16_f32: lo=src0, hi=src1 (RNE)
    asm("v_cvt_pk_bf16_f32 %0, %1, %2" : "=v"(p0) : "v"(a0.x), "v"(a0.y));
    asm("v_cvt_pk_bf16_f32 %0, %1, %2" : "=v"(p1) : "v"(a0.z), "v"(a0.w));
    asm("v_cvt_pk_bf16_f32 %0, %1, %2" : "=v"(p2) : "v"(a1.x), "v"(a1.y));
    asm("v_cvt_pk_bf16_f32 %0, %1, %2" : "=v"(p3) : "v"(a1.z), "v"(a1.w));
    uint4v ap = {p0, p1, p2, p3};
    short8v af = __builtin_bit_cast(short8v, ap);
    #pragma unroll
    for (int ft = 0; ft < 4; ++ft) {
      short8v bfr = *reinterpret_cast<const short8v*>(
          wp + (long)ft * 16 * NIN + s * 32);
      acc[ft] = __builtin_amdgcn_mfma_f32_16x16x32_bf16(af, bfr, acc[ft], 0, 0, 0);
    }
  }

  // D: col(f) = lane&15, row(node) = kg*4 + reg
  int n0 = gw * 16 + kg * 4;
  #pragma unroll
  for (int ft = 0; ft < 4; ++ft) {
    float bias = b[ft * 16 + r16];
    #pragma unroll
    for (int r = 0; r < 4; ++r)
      h[(long)(n0 + r) * NHID + ft * 16 + r16] = f2bf(acc[ft][r] + bias);
  }
}

// ---------- sortb: counting-sort each bucket by row-local index -------------
__global__ __launch_bounds__(256) void sortb_kernel(
    const int* __restrict__ gcur, int2* __restrict__ ecv2,
    int2* __restrict__ rowmeta)
{
  __shared__ int2 ed[BCAP];               // 20.5 KB
  __shared__ unsigned short slots[BCAP];  // 5 KB
  __shared__ int hist[128], base[128], stmp[128];
  int bkt = blockIdx.x;
  int tid = (int)threadIdx.x;

  int n = gcur[bkt];
  if (n > BCAP) n = BCAP;
  int2* bptr = ecv2 + (long)bkt * BCAP;

  if (tid < 128) hist[tid] = 0;
  __syncthreads();

  for (int i = tid; i < n; i += 256) {
    int2 e = bptr[i];
    ed[i] = e;
    int rl = e.x >> 17;
    slots[i] = (unsigned short)atomicAdd(&hist[rl], 1);
  }
  __syncthreads();

  int v = (tid < 128) ? hist[tid] : 0;
  if (tid < 128) stmp[tid] = v;
  __syncthreads();
  for (int d = 1; d < 128; d <<= 1) {
    int t = (tid < 128 && tid >= d) ? stmp[tid - d] : 0;
    __syncthreads();
    if (tid < 128) stmp[tid] += t;
    __syncthreads();
  }
  if (tid < 128) base[tid] = stmp[tid] - v;
  __syncthreads();

  for (int i = tid; i < n; i += 256) {
    int2 e = ed[i];
    int rl = e.x >> 17;
    int pos = base[rl] + (int)slots[i];
    bptr[pos] = make_int2(e.x & 0x1FFFF, e.y);
  }

  if (tid < 128) {
    int row = bkt * 128 + tid;
    if (row < NODES)
      rowmeta[row] = make_int2(bkt * BCAP + base[tid], hist[tid]);
  }
}

// ---------- gather: wave per row, 8 edges in flight, +LeakyReLU -------------
__global__ __launch_bounds__(256) void gather_kernel(
    const int2* __restrict__ rowmeta, const int2* __restrict__ ecv2,
    const unsigned short* __restrict__ h, const float* __restrict__ alpha,
    float* __restrict__ out)
{
  int wid = (int)((blockIdx.x * 256 + threadIdx.x) >> 6);
  if (wid >= NODES) return;
  int lane = (int)(threadIdx.x & 63);
  int eg = lane >> 3;          // edge group 0..7
  int fo = lane & 7;           // feature octet 0..7
  int2 m = rowmeta[wid];
  int deg = m.y;
  const int2* base = ecv2 + m.x;
  float a = alpha[0];

  float acc[8] = {0.f, 0.f, 0.f, 0.f, 0.f, 0.f, 0.f, 0.f};
  int j = eg;
  int2 e = (j < deg) ? base[j] : make_int2(0, 0);
  while (j < deg) {
    int2 en = (j + 8 < deg) ? base[j + 8] : make_int2(0, 0);   // prefetch
    float v = __int_as_float(e.y);
    ushort8v hv = *reinterpret_cast<const ushort8v*>(&h[(long)e.x * NHID + fo * 8]);
    #pragma unroll
    for (int k = 0; k < 8; ++k)
      acc[k] = fmaf(v, bf2f(hv[k]), acc[k]);
    e = en;
    j += 8;
  }

  #pragma unroll
  for (int k = 0; k < 8; ++k) {
    acc[k] += __shfl_xor(acc[k], 8);
    acc[k] += __shfl_xor(acc[k], 16);
    acc[k] += __shfl_xor(acc[k], 32);
  }

  if (eg == 0) {
    float4 o0, o1;
    o0.x = acc[0] >= 0.f ? acc[0] : a * acc[0];
    o0.y = acc[1] >= 0.f ? acc[1] : a * acc[1];
    o0.z = acc[2] >= 0.f ? acc[2] : a * acc[2];
    o0.w = acc[3] >= 0.f ? acc[3] : a * acc[3];
    o1.x = acc[4] >= 0.f ? acc[4] : a * acc[4];
    o1.y = acc[5] >= 0.f ? acc[5] : a * acc[5];
    o1.z = acc[6] >= 0.f ? acc[6] : a * acc[6];
    o1.w = acc[7] >= 0.f ? acc[7] : a * acc[7];
    *reinterpret_cast<float4*>(&out[(long)wid * NHID + fo * 8]) = o0;
    *reinterpret_cast<float4*>(&out[(long)wid * NHID + fo * 8 + 4]) = o1;
  }
}

extern "C" void kernel_launch(void* const* d_in, const int* in_sizes, int n_in,
                              void* d_out, int out_size, void* d_ws, size_t ws_size,
                              hipStream_t stream) {
  const float* x     = (const float*)d_in[0];
  const int*   rows  = (const int*)d_in[1];
  const int*   cols  = (const int*)d_in[2];
  const float* vals  = (const float*)d_in[3];
  const float* W     = (const float*)d_in[4];
  const float* b     = (const float*)d_in[5];
  const float* alpha = (const float*)d_in[6];
  float* out = (float*)d_out;

  float* wsf = (float*)d_ws;
  unsigned short* h     = (unsigned short*)(wsf + H_OFF);
  unsigned int*   wbf   = (unsigned int*)(wsf + WBF_OFF);
  int*            gcur  = (int*)(wsf + GCUR_OFF);
  int2*           rmeta = (int2*)(wsf + RMETA_OFF);
  int2*           ecv2  = (int2*)(wsf + ECV2_OFF);

  init_kernel<<<64, 256, 0, stream>>>(W, wbf, gcur);
  binA_kernel<<<NBA, 256, 0, stream>>>(rows, cols, vals, gcur, ecv2);
  gemm_kernel<<<(NODES / 16 + 3) / 4, 256, 0, stream>>>(
      x, (const unsigned short*)wbf, b, h);
  sortb_kernel<<<NB, 256, 0, stream>>>(gcur, ecv2, rmeta);
  gather_kernel<<<NODES * 64 / 256, 256, 0, stream>>>(rmeta, ecv2, h, alpha, out);
}